// Round 9
// baseline (1640.861 us; speedup 1.0000x reference)
//
#include <hip/hip_runtime.h>

#define D_MODEL 512
#define SEQ     4096
#define BATCH   4
#define M_TOT   (BATCH*SEQ)   // 16384
#define WS_NEEDED ((size_t)2 * M_TOT * D_MODEL * 2)   // node_bf + nodeT_bf: 32 MiB

typedef float  f32x4  __attribute__((ext_vector_type(4)));
typedef __bf16 bf16x8 __attribute__((ext_vector_type(8)));

union FU { float f; unsigned int u; };
__device__ __forceinline__ unsigned short f_to_bf16(float f) {
    FU c; c.f = f;
    unsigned int r = c.u + 0x7fffu + ((c.u >> 16) & 1u);   // RNE
    return (unsigned short)(r >> 16);
}
__device__ __forceinline__ unsigned int pack_bf16(float a, float b) {
    return (unsigned int)f_to_bf16(a) | ((unsigned int)f_to_bf16(b) << 16);
}

// -------- K1: node_bf = relu(x @ W^T + b) via MFMA; + transposed copy ------
extern "C" __global__ __launch_bounds__(256) void proj_kernel(
        const float* __restrict__ x, const float* __restrict__ w,
        const float* __restrict__ bias,
        unsigned short* __restrict__ node_bf, unsigned short* __restrict__ nodeT_bf) {
    __shared__ short Xs[64][72];   // bf16 bits, +8 pad (also transpose buf in epilogue)
    __shared__ short Ws[64][72];
    const int tid  = threadIdx.x;
    const int row0 = blockIdx.x * 64;
    const int col0 = blockIdx.y * 64;
    const int lane = tid & 63;
    const int wv   = tid >> 6;
    const int lr   = lane & 15;
    const int quad = lane >> 4;

    f32x4 acc[4];
    #pragma unroll
    for (int s = 0; s < 4; ++s) acc[s] = (f32x4){0.f,0.f,0.f,0.f};

    for (int kc = 0; kc < D_MODEL; kc += 64) {
        #pragma unroll
        for (int p = 0; p < 2; ++p) {
            int slot = p*256 + tid;
            int r  = slot >> 3, c4 = (slot & 7) * 8;
            float4 a0 = *(const float4*)(x + (size_t)(row0 + r)*D_MODEL + kc + c4);
            float4 a1 = *(const float4*)(x + (size_t)(row0 + r)*D_MODEL + kc + c4 + 4);
            *(unsigned int*)&Xs[r][c4+0] = pack_bf16(a0.x, a0.y);
            *(unsigned int*)&Xs[r][c4+2] = pack_bf16(a0.z, a0.w);
            *(unsigned int*)&Xs[r][c4+4] = pack_bf16(a1.x, a1.y);
            *(unsigned int*)&Xs[r][c4+6] = pack_bf16(a1.z, a1.w);
            float4 b0 = *(const float4*)(w + (size_t)(col0 + r)*D_MODEL + kc + c4);
            float4 b1 = *(const float4*)(w + (size_t)(col0 + r)*D_MODEL + kc + c4 + 4);
            *(unsigned int*)&Ws[r][c4+0] = pack_bf16(b0.x, b0.y);
            *(unsigned int*)&Ws[r][c4+2] = pack_bf16(b0.z, b0.w);
            *(unsigned int*)&Ws[r][c4+4] = pack_bf16(b1.x, b1.y);
            *(unsigned int*)&Ws[r][c4+6] = pack_bf16(b1.z, b1.w);
        }
        __syncthreads();
        #pragma unroll
        for (int t = 0; t < 2; ++t) {
            bf16x8 a = *reinterpret_cast<const bf16x8*>(&Xs[wv*16 + lr][t*32 + quad*8]);
            #pragma unroll
            for (int s = 0; s < 4; ++s) {
                bf16x8 bb = *reinterpret_cast<const bf16x8*>(&Ws[s*16 + lr][t*32 + quad*8]);
                acc[s] = __builtin_amdgcn_mfma_f32_16x16x32_bf16(a, bb, acc[s], 0, 0, 0);
            }
        }
        __syncthreads();
    }
    #pragma unroll
    for (int s = 0; s < 4; ++s) {
        int n = col0 + s*16 + lr;
        float bv = bias[n];
        #pragma unroll
        for (int r = 0; r < 4; ++r) {
            int m_local = wv*16 + quad*4 + r;   // C/D: row=quad*4+reg, col=lr (HW-verified R7)
            float v = acc[s][r] + bv;
            v = v > 0.0f ? v : 0.0f;
            unsigned short us = f_to_bf16(v);
            node_bf[(size_t)(row0 + m_local)*D_MODEL + n] = us;
            Xs[s*16 + lr][m_local] = (short)us;   // T[n_local][m_local]
        }
    }
    __syncthreads();
    {
        const int b = row0 >> 12, si0 = row0 & 4095;
        #pragma unroll
        for (int p = 0; p < 2; ++p) {
            int slot = p*256 + tid;
            int r = slot >> 3, c8 = (slot & 7) * 8;
            int4 val = *(int4*)&Xs[r][c8];
            *(int4*)&nodeT_bf[((size_t)(b*D_MODEL + col0 + r))*SEQ + si0 + c8] = val;
        }
    }
}

// -------- K2: flash attention, BARRIER-FREE K-loop ------------------------
// B-operand fragments read directly from global (L1 serves 4-wave reuse);
// only wave-private Ps LDS remains (no __syncthreads in the loop).
extern "C" __global__ __launch_bounds__(256) void flash_kernel(
        const unsigned short* __restrict__ node,
        const unsigned short* __restrict__ nodeT,
        float* __restrict__ out) {
    __shared__ short Ps[4][16][40];   // per-wave P tile, +8 pad (wave-private)
    const int tid  = threadIdx.x;
    const int lane = tid & 63;
    const int wv   = tid >> 6;
    const int lr   = lane & 15;
    const int quad = lane >> 4;
    const int bb   = blockIdx.y;
    const int q0   = blockIdx.x * 64;

    const unsigned short* nb  = node  + (size_t)bb * SEQ * D_MODEL;
    const unsigned short* ntb = nodeT + (size_t)bb * D_MODEL * SEQ;

    // Q fragments: A[m=lr][k = t*32 + quad*8 + j]
    bf16x8 qf[16];
    const int qrow = q0 + wv*16 + lr;
    #pragma unroll
    for (int t = 0; t < 16; ++t)
        qf[t] = *reinterpret_cast<const bf16x8*>(&nb[(size_t)qrow*D_MODEL + t*32 + quad*8]);

    f32x4 o[32];
    #pragma unroll
    for (int n = 0; n < 32; ++n) o[n] = (f32x4){0.f,0.f,0.f,0.f};
    float m_run[4] = {-3.0e38f,-3.0e38f,-3.0e38f,-3.0e38f};
    float l_run[4] = {0.f,0.f,0.f,0.f};

    for (int kt = 0; kt < SEQ/32; ++kt) {
        // ---- S = Q K^T : K B-fragments straight from row-major node ----
        // kb lane address: key row (kt*32 + s*16 + lr), d = t*32 + quad*8 (16 B contiguous)
        const unsigned short* kb0base = nb + (size_t)(kt*32 + lr)*D_MODEL + quad*8;
        const unsigned short* kb1base = kb0base + (size_t)16*D_MODEL;
        f32x4 sacc0 = (f32x4){0.f,0.f,0.f,0.f};
        f32x4 sacc1 = (f32x4){0.f,0.f,0.f,0.f};
        #pragma unroll
        for (int t = 0; t < 16; ++t) {
            bf16x8 kb0 = *reinterpret_cast<const bf16x8*>(kb0base + t*32);
            bf16x8 kb1 = *reinterpret_cast<const bf16x8*>(kb1base + t*32);
            sacc0 = __builtin_amdgcn_mfma_f32_16x16x32_bf16(qf[t], kb0, sacc0, 0, 0, 0);
            sacc1 = __builtin_amdgcn_mfma_f32_16x16x32_bf16(qf[t], kb1, sacc1, 0, 0, 0);
        }

        // ---- online softmax (C/D: row = quad*4+r, col = lr) ----
        float alpha[4];
        #pragma unroll
        for (int r = 0; r < 4; ++r) {
            float mx = fmaxf(sacc0[r], sacc1[r]);
            #pragma unroll
            for (int off = 1; off < 16; off <<= 1)
                mx = fmaxf(mx, __shfl_xor(mx, off));
            float mnew = fmaxf(m_run[r], mx);
            alpha[r] = __expf(m_run[r] - mnew);
            float p0 = __expf(sacc0[r] - mnew);
            float p1 = __expf(sacc1[r] - mnew);
            m_run[r] = mnew;
            float rs = p0 + p1;
            #pragma unroll
            for (int off = 1; off < 16; off <<= 1)
                rs += __shfl_xor(rs, off);
            l_run[r] = l_run[r]*alpha[r] + rs;
            // wave-private C->A transform (no barrier needed)
            Ps[wv][quad*4 + r][lr]      = (short)f_to_bf16(p0);
            Ps[wv][quad*4 + r][16 + lr] = (short)f_to_bf16(p1);
        }
        #pragma unroll
        for (int n = 0; n < 32; ++n) {
            #pragma unroll
            for (int r = 0; r < 4; ++r) o[n][r] *= alpha[r];
        }
        bf16x8 pa = *reinterpret_cast<const bf16x8*>(&Ps[wv][lr][quad*8]);

        // ---- O += P V : V^T B-fragments straight from nodeT ----
        // vb lane address: d row (n*16 + lr), key = kt*32 + quad*8 (16 B contiguous)
        const unsigned short* vbase = ntb + (size_t)lr*SEQ + kt*32 + quad*8;
        #pragma unroll
        for (int n = 0; n < 32; ++n) {
            bf16x8 vb = *reinterpret_cast<const bf16x8*>(vbase + (size_t)n*16*SEQ);
            o[n] = __builtin_amdgcn_mfma_f32_16x16x32_bf16(pa, vb, o[n], 0, 0, 0);
        }
    }

    // epilogue: out = O / l (fp32); o[n] covers d = n*16 + lr
    #pragma unroll
    for (int r = 0; r < 4; ++r) {
        float inv = 1.0f / l_run[r];
        int row = q0 + wv*16 + quad*4 + r;
        float* obase = out + ((size_t)bb * SEQ + row) * D_MODEL;
        #pragma unroll
        for (int n = 0; n < 32; ++n)
            obase[n*16 + lr] = o[n][r] * inv;
    }
}

extern "C" void kernel_launch(void* const* d_in, const int* in_sizes, int n_in,
                              void* d_out, int out_size, void* d_ws, size_t ws_size,
                              hipStream_t stream) {
    const float* x = (const float*)d_in[0];
    const float* w = (const float*)d_in[1];
    const float* b = (const float*)d_in[2];
    float* out = (float*)d_out;
    unsigned short* node_bf  = (unsigned short*)d_ws;
    unsigned short* nodeT_bf = node_bf + (size_t)M_TOT * D_MODEL;
    const size_t out_bytes = (size_t)out_size * 4;

    if (d_ws == 0 || ws_size < WS_NEEDED) {
        (void)hipMemsetAsync(d_out, 0x4F, out_bytes, stream);   // ws sentinel
        return;
    }

    (void)hipGetLastError();
    proj_kernel<<<dim3(M_TOT/64, D_MODEL/64), dim3(256), 0, stream>>>(x, w, b, node_bf, nodeT_bf);
    hipError_t ep = hipGetLastError();
    flash_kernel<<<dim3(SEQ/64, BATCH), dim3(256), 0, stream>>>(node_bf, nodeT_bf, out);
    hipError_t ef = hipGetLastError();

    if (ep != hipSuccess) {
        (void)hipMemsetAsync(d_out, 0x49, out_bytes, stream);   // proj launch fail
    } else if (ef != hipSuccess) {
        (void)hipMemsetAsync(d_out, 0x4B, out_bytes, stream);   // flash launch fail
    }
}

// Round 10
// 860.133 us; speedup vs baseline: 1.9077x; 1.9077x over previous
//
#include <hip/hip_runtime.h>

#define D_MODEL 512
#define SEQ     4096
#define BATCH   4
#define M_TOT   (BATCH*SEQ)   // 16384
#define WS_NEEDED ((size_t)2 * M_TOT * D_MODEL * 2)   // node_bf + nodeT_bf: 32 MiB

typedef float  f32x4  __attribute__((ext_vector_type(4)));
typedef __bf16 bf16x8 __attribute__((ext_vector_type(8)));

union FU { float f; unsigned int u; };
__device__ __forceinline__ unsigned short f_to_bf16(float f) {
    FU c; c.f = f;
    unsigned int r = c.u + 0x7fffu + ((c.u >> 16) & 1u);   // RNE
    return (unsigned short)(r >> 16);
}
__device__ __forceinline__ unsigned int pack_bf16(float a, float b) {
    return (unsigned int)f_to_bf16(a) | ((unsigned int)f_to_bf16(b) << 16);
}

// -------- K1: node_bf = relu(x @ W^T + b) via MFMA; + transposed copy ------
extern "C" __global__ __launch_bounds__(256) void proj_kernel(
        const float* __restrict__ x, const float* __restrict__ w,
        const float* __restrict__ bias,
        unsigned short* __restrict__ node_bf, unsigned short* __restrict__ nodeT_bf) {
    __shared__ short Xs[64][72];
    __shared__ short Ws[64][72];
    const int tid  = threadIdx.x;
    const int row0 = blockIdx.x * 64;
    const int col0 = blockIdx.y * 64;
    const int lane = tid & 63;
    const int wv   = tid >> 6;
    const int lr   = lane & 15;
    const int quad = lane >> 4;

    f32x4 acc[4];
    #pragma unroll
    for (int s = 0; s < 4; ++s) acc[s] = (f32x4){0.f,0.f,0.f,0.f};

    for (int kc = 0; kc < D_MODEL; kc += 64) {
        #pragma unroll
        for (int p = 0; p < 2; ++p) {
            int slot = p*256 + tid;
            int r  = slot >> 3, c4 = (slot & 7) * 8;
            float4 a0 = *(const float4*)(x + (size_t)(row0 + r)*D_MODEL + kc + c4);
            float4 a1 = *(const float4*)(x + (size_t)(row0 + r)*D_MODEL + kc + c4 + 4);
            *(unsigned int*)&Xs[r][c4+0] = pack_bf16(a0.x, a0.y);
            *(unsigned int*)&Xs[r][c4+2] = pack_bf16(a0.z, a0.w);
            *(unsigned int*)&Xs[r][c4+4] = pack_bf16(a1.x, a1.y);
            *(unsigned int*)&Xs[r][c4+6] = pack_bf16(a1.z, a1.w);
            float4 b0 = *(const float4*)(w + (size_t)(col0 + r)*D_MODEL + kc + c4);
            float4 b1 = *(const float4*)(w + (size_t)(col0 + r)*D_MODEL + kc + c4 + 4);
            *(unsigned int*)&Ws[r][c4+0] = pack_bf16(b0.x, b0.y);
            *(unsigned int*)&Ws[r][c4+2] = pack_bf16(b0.z, b0.w);
            *(unsigned int*)&Ws[r][c4+4] = pack_bf16(b1.x, b1.y);
            *(unsigned int*)&Ws[r][c4+6] = pack_bf16(b1.z, b1.w);
        }
        __syncthreads();
        #pragma unroll
        for (int t = 0; t < 2; ++t) {
            bf16x8 a = *reinterpret_cast<const bf16x8*>(&Xs[wv*16 + lr][t*32 + quad*8]);
            #pragma unroll
            for (int s = 0; s < 4; ++s) {
                bf16x8 bb = *reinterpret_cast<const bf16x8*>(&Ws[s*16 + lr][t*32 + quad*8]);
                acc[s] = __builtin_amdgcn_mfma_f32_16x16x32_bf16(a, bb, acc[s], 0, 0, 0);
            }
        }
        __syncthreads();
    }
    #pragma unroll
    for (int s = 0; s < 4; ++s) {
        int n = col0 + s*16 + lr;
        float bv = bias[n];
        #pragma unroll
        for (int r = 0; r < 4; ++r) {
            int m_local = wv*16 + quad*4 + r;   // C/D: row=quad*4+reg, col=lr (HW-verified R7)
            float v = acc[s][r] + bv;
            v = v > 0.0f ? v : 0.0f;
            unsigned short us = f_to_bf16(v);
            node_bf[(size_t)(row0 + m_local)*D_MODEL + n] = us;
            Xs[s*16 + lr][m_local] = (short)us;
        }
    }
    __syncthreads();
    {
        const int b = row0 >> 12, si0 = row0 & 4095;
        #pragma unroll
        for (int p = 0; p < 2; ++p) {
            int slot = p*256 + tid;
            int r = slot >> 3, c8 = (slot & 7) * 8;
            int4 val = *(int4*)&Xs[r][c8];
            *(int4*)&nodeT_bf[((size_t)(b*D_MODEL + col0 + r))*SEQ + si0 + c8] = val;
        }
    }
}

// -------- K2: flash attention, R7 structure + register prefetch ------------
// LDS: Ks 33280 + Vt 20480 + Ps 5120 = 58880 B.
// Global loads for tile k+1 are issued ~1 full iteration before their
// ds_write consumes them; barriers wait only on LDS (lgkm) drains.
extern "C" __global__ __launch_bounds__(256) void flash_kernel(
        const unsigned short* __restrict__ node,
        const unsigned short* __restrict__ nodeT,
        float* __restrict__ out) {
    __shared__ short Ks[32][520];     // 32 keys x 512 d, +8 pad
    __shared__ short Vt[256][40];     // half V^T (256 d x 32 keys), +8 pad
    __shared__ short Ps[4][16][40];   // per-wave P tile, +8 pad
    const int tid  = threadIdx.x;
    const int lane = tid & 63;
    const int wv   = tid >> 6;
    const int lr   = lane & 15;
    const int quad = lane >> 4;
    const int bb   = blockIdx.y;
    const int q0   = blockIdx.x * 64;

    const unsigned short* nb  = node  + (size_t)bb * SEQ * D_MODEL;
    const unsigned short* ntb = nodeT + (size_t)bb * D_MODEL * SEQ;

    // staging slot geometry (loop-invariant)
    const int kr  = tid >> 3;              // for K: slot p*256+tid -> row (slot>>6)... per-p below
    (void)kr;

    // Q fragments: A[m=lr][k = t*32 + quad*8 + j]
    bf16x8 qf[16];
    const int qrow = q0 + wv*16 + lr;
    #pragma unroll
    for (int t = 0; t < 16; ++t)
        qf[t] = *reinterpret_cast<const bf16x8*>(&nb[(size_t)qrow*D_MODEL + t*32 + quad*8]);

    f32x4 o[32];
    #pragma unroll
    for (int n = 0; n < 32; ++n) o[n] = (f32x4){0.f,0.f,0.f,0.f};
    float m_run[4] = {-3.0e38f,-3.0e38f,-3.0e38f,-3.0e38f};
    float l_run[4] = {0.f,0.f,0.f,0.f};

    // ---- prologue: prefetch tile 0 into registers ----
    int4 pK[8], pV0[4], pV1[4];
    #pragma unroll
    for (int p = 0; p < 8; ++p) {
        int slot = p*256 + tid;
        int r = slot >> 6, c8 = (slot & 63) * 8;
        pK[p] = *(const int4*)&nb[(size_t)r*D_MODEL + c8];
    }
    #pragma unroll
    for (int p = 0; p < 4; ++p) {
        int slot = p*256 + tid;
        int d = slot >> 2, c8 = (slot & 3) * 8;
        pV0[p] = *(const int4*)&ntb[(size_t)d*SEQ + c8];
        pV1[p] = *(const int4*)&ntb[(size_t)(256 + d)*SEQ + c8];
    }

    for (int kt = 0; kt < SEQ/32; ++kt) {
        const int ktn = (kt + 1) & (SEQ/32 - 1);   // clamp-wrap; last prefetch harmless

        __syncthreads();   // A: prior iter's Ks/Vt reads complete
        #pragma unroll
        for (int p = 0; p < 8; ++p) {
            int slot = p*256 + tid;
            int r = slot >> 6, c8 = (slot & 63) * 8;
            *(int4*)&Ks[r][c8] = pK[p];
        }
        #pragma unroll
        for (int p = 0; p < 4; ++p) {
            int slot = p*256 + tid;
            int d = slot >> 2, c8 = (slot & 3) * 8;
            *(int4*)&Vt[d][c8] = pV0[p];
        }
        __syncthreads();   // B: staged tile visible

        // issue next-tile K and V-half0 loads (consumed next iter at A/B)
        #pragma unroll
        for (int p = 0; p < 8; ++p) {
            int slot = p*256 + tid;
            int r = slot >> 6, c8 = (slot & 63) * 8;
            pK[p] = *(const int4*)&nb[(size_t)(ktn*32 + r)*D_MODEL + c8];
        }
        #pragma unroll
        for (int p = 0; p < 4; ++p) {
            int slot = p*256 + tid;
            int d = slot >> 2, c8 = (slot & 3) * 8;
            pV0[p] = *(const int4*)&ntb[(size_t)d*SEQ + ktn*32 + c8];
        }

        // ---- S = Q K^T ----
        f32x4 sacc0 = (f32x4){0.f,0.f,0.f,0.f};
        f32x4 sacc1 = (f32x4){0.f,0.f,0.f,0.f};
        #pragma unroll
        for (int t = 0; t < 16; ++t) {
            bf16x8 kb0 = *reinterpret_cast<const bf16x8*>(&Ks[lr][t*32 + quad*8]);
            bf16x8 kb1 = *reinterpret_cast<const bf16x8*>(&Ks[16 + lr][t*32 + quad*8]);
            sacc0 = __builtin_amdgcn_mfma_f32_16x16x32_bf16(qf[t], kb0, sacc0, 0, 0, 0);
            sacc1 = __builtin_amdgcn_mfma_f32_16x16x32_bf16(qf[t], kb1, sacc1, 0, 0, 0);
        }

        // ---- online softmax (C/D: row = quad*4+r, col = lr) ----
        float alpha[4];
        #pragma unroll
        for (int r = 0; r < 4; ++r) {
            float mx = fmaxf(sacc0[r], sacc1[r]);
            #pragma unroll
            for (int off = 1; off < 16; off <<= 1)
                mx = fmaxf(mx, __shfl_xor(mx, off));
            float mnew = fmaxf(m_run[r], mx);
            alpha[r] = __expf(m_run[r] - mnew);
            float p0 = __expf(sacc0[r] - mnew);
            float p1 = __expf(sacc1[r] - mnew);
            m_run[r] = mnew;
            float rs = p0 + p1;
            #pragma unroll
            for (int off = 1; off < 16; off <<= 1)
                rs += __shfl_xor(rs, off);
            l_run[r] = l_run[r]*alpha[r] + rs;
            Ps[wv][quad*4 + r][lr]      = (short)f_to_bf16(p0);
            Ps[wv][quad*4 + r][16 + lr] = (short)f_to_bf16(p1);
        }
        #pragma unroll
        for (int n = 0; n < 32; ++n) {
            #pragma unroll
            for (int r = 0; r < 4; ++r) o[n][r] *= alpha[r];
        }
        bf16x8 pa = *reinterpret_cast<const bf16x8*>(&Ps[wv][lr][quad*8]);

        // ---- PV half 0 (d-blocks 0..15) ----
        #pragma unroll
        for (int n = 0; n < 16; ++n) {
            bf16x8 vb = *reinterpret_cast<const bf16x8*>(&Vt[n*16 + lr][quad*8]);
            o[n] = __builtin_amdgcn_mfma_f32_16x16x32_bf16(pa, vb, o[n], 0, 0, 0);
        }
        __syncthreads();   // C: Vt half-0 reads done

        // stage V-half1 from prefetch regs
        #pragma unroll
        for (int p = 0; p < 4; ++p) {
            int slot = p*256 + tid;
            int d = slot >> 2, c8 = (slot & 3) * 8;
            *(int4*)&Vt[d][c8] = pV1[p];
        }
        __syncthreads();   // D: half-1 visible

        // issue next-tile V-half1 loads
        #pragma unroll
        for (int p = 0; p < 4; ++p) {
            int slot = p*256 + tid;
            int d = slot >> 2, c8 = (slot & 3) * 8;
            pV1[p] = *(const int4*)&ntb[(size_t)(256 + d)*SEQ + ktn*32 + c8];
        }

        // ---- PV half 1 (d-blocks 16..31) ----
        #pragma unroll
        for (int n = 16; n < 32; ++n) {
            bf16x8 vb = *reinterpret_cast<const bf16x8*>(&Vt[(n-16)*16 + lr][quad*8]);
            o[n] = __builtin_amdgcn_mfma_f32_16x16x32_bf16(pa, vb, o[n], 0, 0, 0);
        }
    }

    // epilogue: out = O / l (fp32); o[n] covers d = n*16 + lr
    #pragma unroll
    for (int r = 0; r < 4; ++r) {
        float inv = 1.0f / l_run[r];
        int row = q0 + wv*16 + quad*4 + r;
        float* obase = out + ((size_t)bb * SEQ + row) * D_MODEL;
        #pragma unroll
        for (int n = 0; n < 32; ++n)
            obase[n*16 + lr] = o[n][r] * inv;
    }
}

extern "C" void kernel_launch(void* const* d_in, const int* in_sizes, int n_in,
                              void* d_out, int out_size, void* d_ws, size_t ws_size,
                              hipStream_t stream) {
    const float* x = (const float*)d_in[0];
    const float* w = (const float*)d_in[1];
    const float* b = (const float*)d_in[2];
    float* out = (float*)d_out;
    unsigned short* node_bf  = (unsigned short*)d_ws;
    unsigned short* nodeT_bf = node_bf + (size_t)M_TOT * D_MODEL;
    const size_t out_bytes = (size_t)out_size * 4;

    if (d_ws == 0 || ws_size < WS_NEEDED) {
        (void)hipMemsetAsync(d_out, 0x4F, out_bytes, stream);
        return;
    }

    (void)hipGetLastError();
    proj_kernel<<<dim3(M_TOT/64, D_MODEL/64), dim3(256), 0, stream>>>(x, w, b, node_bf, nodeT_bf);
    hipError_t ep = hipGetLastError();
    flash_kernel<<<dim3(SEQ/64, BATCH), dim3(256), 0, stream>>>(node_bf, nodeT_bf, out);
    hipError_t ef = hipGetLastError();

    if (ep != hipSuccess) {
        (void)hipMemsetAsync(d_out, 0x49, out_bytes, stream);
    } else if (ef != hipSuccess) {
        (void)hipMemsetAsync(d_out, 0x4B, out_bytes, stream);
    }
}